// Round 5
// baseline (220.566 us; speedup 1.0000x reference)
//
#include <hip/hip_runtime.h>
#include <stdint.h>

#define B_   8
#define N1_  2048
#define N2_  8192

typedef unsigned short ushort_t;
typedef __attribute__((ext_vector_type(8))) short short8;
typedef __attribute__((ext_vector_type(8))) unsigned short ushort8;
typedef __attribute__((ext_vector_type(4))) unsigned short ushort4v;
typedef __attribute__((ext_vector_type(4))) float f32x4;

__device__ __forceinline__ float b2f(unsigned short u) {
  union { unsigned int i; float f; } v;
  v.i = ((unsigned int)u) << 16;
  return v.f;
}
__device__ __forceinline__ unsigned short f2b(float f) {  // RNE bf16 round
  unsigned int x = __builtin_bit_cast(unsigned int, f);
  unsigned int r = x + 0x7FFFu + ((x >> 16) & 1u);
  return (unsigned short)(r >> 16);
}
__device__ __forceinline__ f32x4 mfma16(ushort8 a, ushort8 b, f32x4 c) {
  return __builtin_amdgcn_mfma_f32_16x16x32_bf16(
      __builtin_bit_cast(short8, a), __builtin_bit_cast(short8, b), c, 0, 0, 0);
}
__device__ __forceinline__ void gl_lds16(const void* gsrc, void* ldst) {
  __builtin_amdgcn_global_load_lds(
      (const __attribute__((address_space(1))) unsigned int*)(uintptr_t)gsrc,
      (__attribute__((address_space(3))) unsigned int*)(uint32_t)(uintptr_t)ldst,
      16, 0, 0);
}

// ---- three_nn + interp fused: writes xcat[m][384] cols 0..255 -------------------
__global__ __launch_bounds__(256) void k_three_nn(const float* __restrict__ xyz2,
                                                  const float* __restrict__ xyz1,
                                                  const ushort_t* __restrict__ f1tb,
                                                  ushort_t* __restrict__ xcat) {
  __shared__ __align__(16) float sm[3][2080];
  const int b = blockIdx.y;
  const float* p1 = xyz1 + (size_t)b * 3 * N1_;
  for (int i = threadIdx.x; i < N1_; i += 256) {
    const int a = (i >> 9) * 520 + (i & 511);
    sm[0][a] = p1[i];
    sm[1][a] = p1[N1_ + i];
    sm[2][a] = p1[2 * N1_ + i];
  }
  __syncthreads();

  const int lane = threadIdx.x & 63;
  const int q = threadIdx.x >> 2, c = threadIdx.x & 3;
  const int n = blockIdx.x * 64 + q;
  const float px = xyz2[(size_t)b * 3 * N2_ + n];
  const float py = xyz2[(size_t)b * 3 * N2_ + N2_ + n];
  const float pz = xyz2[(size_t)b * 3 * N2_ + 2 * N2_ + n];

  float dk0 = 3.4e38f, dk1 = 3.4e38f, dk2 = 3.4e38f;
  int ik0 = 0, ik1 = 0, ik2 = 0;
  const float* mx = &sm[0][c * 520];
  const float* my = &sm[1][c * 520];
  const float* mz = &sm[2][c * 520];

  // exact insert: cmps on OLD values, dist update via med3 (3 ops), idx via cndmask
#define INS(DD, II)                                   \
  {                                                   \
    const float d_ = (DD); const int i_ = (II);       \
    const bool c0_ = d_ < dk0;                        \
    const bool c1_ = d_ < dk1;                        \
    const bool c2_ = d_ < dk2;                        \
    ik2 = c2_ ? (c1_ ? ik1 : i_) : ik2;               \
    ik1 = c1_ ? (c0_ ? ik0 : i_) : ik1;               \
    ik0 = c0_ ? i_ : ik0;                             \
    dk2 = __builtin_amdgcn_fmed3f(dk1, dk2, d_);      \
    dk1 = __builtin_amdgcn_fmed3f(dk0, dk1, d_);      \
    dk0 = fminf(dk0, d_);                             \
  }

  const int ib = c * 512;
  for (int i = 0; i < 512; i += 8) {
    const float4 xa = *(const float4*)(mx + i);
    const float4 ya = *(const float4*)(my + i);
    const float4 za = *(const float4*)(mz + i);
    const float4 xb = *(const float4*)(mx + i + 4);
    const float4 yb = *(const float4*)(my + i + 4);
    const float4 zb = *(const float4*)(mz + i + 4);
#define CAND(J, XX, YY, ZZ)                                 \
    {                                                       \
      const float dx = (XX) - px;                           \
      const float dy = (YY) - py;                           \
      const float dz = (ZZ) - pz;                           \
      const float dd = fmaf(dx, dx, fmaf(dy, dy, dz * dz)); \
      INS(dd, ib + i + (J))                                 \
    }
    CAND(0, xa.x, ya.x, za.x) CAND(1, xa.y, ya.y, za.y)
    CAND(2, xa.z, ya.z, za.z) CAND(3, xa.w, ya.w, za.w)
    CAND(4, xb.x, yb.x, zb.x) CAND(5, xb.y, yb.y, zb.y)
    CAND(6, xb.z, yb.z, zb.z) CAND(7, xb.w, yb.w, zb.w)
#undef CAND
  }

  // butterfly merge across the 4 chunk lanes (values identical on all lanes after)
#pragma unroll
  for (int d = 1; d <= 2; d <<= 1) {
    const float r0 = __shfl_xor(dk0, d);
    const float r1 = __shfl_xor(dk1, d);
    const float r2 = __shfl_xor(dk2, d);
    const int s0 = __shfl_xor(ik0, d);
    const int s1 = __shfl_xor(ik1, d);
    const int s2 = __shfl_xor(ik2, d);
    INS(r0, s0) INS(r1, s1) INS(r2, s2)
  }
#undef INS

  // tie-correct indices live on the quad leader (lowest chunk) -> broadcast
  const int lq = lane & ~3;
  const int i0 = __shfl(ik0, lq);
  const int i1 = __shfl(ik1, lq);
  const int i2 = __shfl(ik2, lq);
  const float e0 = fmaxf(dk0, 1e-10f);
  const float e1 = fmaxf(dk1, 1e-10f);
  const float e2 = fmaxf(dk2, 1e-10f);
  const float v0 = 1.0f / e0, v1 = 1.0f / e1, v2 = 1.0f / e2;
  const float rs = 1.0f / (v0 + v1 + v2);
  const float w0 = v0 * rs, w1 = v1 * rs, w2 = v2 * rs;

  // fused interp: each chunk-thread writes its 64-channel slice of xcat row n
  const ushort_t* f1base = f1tb + (size_t)b * (N1_ * 256) + c * 64;
  const ushort_t* r0p = f1base + (size_t)i0 * 256;
  const ushort_t* r1p = f1base + (size_t)i1 * 256;
  const ushort_t* r2p = f1base + (size_t)i2 * 256;
  ushort_t* outp = xcat + ((size_t)b * N2_ + n) * 384 + c * 64;
#pragma unroll
  for (int u = 0; u < 8; ++u) {
    const ushort8 a8 = *(const ushort8*)&r0p[u * 8];
    const ushort8 b8 = *(const ushort8*)&r1p[u * 8];
    const ushort8 c8 = *(const ushort8*)&r2p[u * 8];
    ushort8 o;
#pragma unroll
    for (int j = 0; j < 8; ++j)
      o[j] = f2b(w0 * b2f(a8[j]) + w1 * b2f(b8[j]) + w2 * b2f(c8[j]));
    *(ushort8*)&outp[u * 8] = o;
  }
}

// ------------- transpose + f32->bf16: feat1[b][256][2048] -> f1tb[(b*2048+n)][256] --
__global__ __launch_bounds__(256) void k_tcvt(const float* __restrict__ in,
                                              ushort_t* __restrict__ out, int R, int C) {
  __shared__ float t[32][33];
  const int b = blockIdx.z;
  const float* pin = in + (size_t)b * R * C;
  ushort_t* pout = out + (size_t)b * R * C;
  const int c0 = blockIdx.x * 32, r0 = blockIdx.y * 32;
  const int tx = threadIdx.x, ty = threadIdx.y;
#pragma unroll
  for (int j = 0; j < 4; ++j)
    t[ty * 4 + j][tx] = pin[(size_t)(r0 + ty * 4 + j) * C + c0 + tx];
  __syncthreads();
#pragma unroll
  for (int j = 0; j < 4; ++j)
    pout[(size_t)(c0 + ty * 4 + j) * R + r0 + tx] = f2b(t[tx][ty * 4 + j]);
}

// ---- feat2[b][128][8192] -> xcat[m][384] cols 256..383 (transpose + cvt) ---------
__global__ __launch_bounds__(256) void k_t2x(const float* __restrict__ feat2,
                                             ushort_t* __restrict__ xcat) {
  __shared__ float t[32][33];
  const int b = blockIdx.z;
  const int n0 = blockIdx.x * 32, c0 = blockIdx.y * 32;
  const int tx = threadIdx.x, ty = threadIdx.y;
  const float* pin = feat2 + (size_t)b * 128 * N2_;
#pragma unroll
  for (int j = 0; j < 4; ++j)
    t[ty * 4 + j][tx] = pin[(size_t)(c0 + ty * 4 + j) * N2_ + n0 + tx];
  __syncthreads();
  const int tt = ty * 32 + tx;
  const int nr = tt >> 3, cg = tt & 7;
  ushort4v o;
#pragma unroll
  for (int j = 0; j < 4; ++j)
    o[j] = f2b(t[cg * 4 + j][nr]);
  *(ushort4v*)&xcat[((size_t)b * N2_ + n0 + nr) * 384 + 256 + c0 + cg * 4] = o;
}

// ---------------- W1 + W2 f32 -> bf16 in one launch ----------------
__global__ __launch_bounds__(256) void k_wcvt2(const float* __restrict__ W1,
                                               const float* __restrict__ W2,
                                               ushort_t* __restrict__ W1b,
                                               ushort_t* __restrict__ W2b) {
  const int i = (blockIdx.x * 256 + threadIdx.x) * 4;
  const float* src; ushort_t* dst; int off;
  if (i < 98304) { src = W1; dst = W1b; off = i; }
  else { off = i - 98304; if (off >= 65536) return; src = W2; dst = W2b; }
  const float4 v = *(const float4*)&src[off];
  ushort4v o;
  o[0] = f2b(v.x); o[1] = f2b(v.y); o[2] = f2b(v.z); o[3] = f2b(v.w);
  *(ushort4v*)&dst[off] = o;
}

// ---------------- GEMM1: y1[m][256] = xcat x W1^T, pure MFMA bf16 ----------------
__global__ __launch_bounds__(512, 4) void k_gemm1(
    const ushort_t* __restrict__ xcat, const ushort_t* __restrict__ Wb,
    ushort_t* __restrict__ y1, float* __restrict__ part) {
  __shared__ __align__(16) ushort_t As[2][128 * 72];
  __shared__ __align__(16) ushort_t Bs[256 * 64];
  __shared__ float sRedS[512];
  __shared__ float sRedQ[512];

  const int tid = threadIdx.x;
  const int gm0 = blockIdx.x * 128;
  const int lane = tid & 63, wv = tid >> 6;
  const int wm = wv >> 2, wn = wv & 3;
  const int la = lane & 15, qg = lane >> 4;
  const int m0 = wm * 64, o0 = wn * 64;
  const int ar = tid >> 3, ac = tid & 7, rb2 = ar + 64;

  f32x4 acc[4][4];
#pragma unroll
  for (int mi = 0; mi < 4; ++mi)
#pragma unroll
    for (int ni = 0; ni < 4; ++ni) acc[mi][ni] = 0.0f;

  ushort8 g0, g3;
  auto LOAD_A = [&](int ch) {
    const size_t base = (size_t)(gm0 + ar) * 384 + ch * 64 + ac * 8;
    g0 = *(const ushort8*)&xcat[base];
    g3 = *(const ushort8*)&xcat[base + (size_t)64 * 384];
  };
  auto PROC_A = [&](int dst) {
    *(ushort8*)&As[dst][ar * 72 + ac * 8] = g0;
    *(ushort8*)&As[dst][rb2 * 72 + ac * 8] = g3;
  };
  auto STAGE_B = [&](int ch) {
    const int kbase = ch * 64;
#pragma unroll
    for (int i = 0; i < 4; ++i) {
      const int fc = i * 512 + tid;
      const int row = fc >> 3, p = fc & 7;
      const int cc = p ^ (row & 7);
      gl_lds16(&Wb[(size_t)row * 384 + kbase + cc * 8], &Bs[i * 4096 + wv * 512]);
    }
  };
  auto COMPUTE = [&](int src) {
#pragma unroll
    for (int ks = 0; ks < 2; ++ks) {
      ushort8 af[4], bfr[4];
#pragma unroll
      for (int mi = 0; mi < 4; ++mi)
        af[mi] = *(const ushort8*)&As[src][(m0 + mi * 16 + la) * 72 + (ks * 4 + qg) * 8];
#pragma unroll
      for (int ni = 0; ni < 4; ++ni) {
        const int ro = o0 + ni * 16 + la;
        bfr[ni] = *(const ushort8*)&Bs[ro * 64 + (((ks * 4 + qg) ^ (ro & 7))) * 8];
      }
#pragma unroll
      for (int mi = 0; mi < 4; ++mi)
#pragma unroll
        for (int ni = 0; ni < 4; ++ni)
          acc[mi][ni] = mfma16(af[mi], bfr[ni], acc[mi][ni]);
    }
  };

  STAGE_B(0); LOAD_A(0); PROC_A(0);
  __syncthreads();
  int buf = 0;
  for (int ch = 0; ch < 6; ++ch) {
    if (ch < 5) LOAD_A(ch + 1);
    COMPUTE(buf);
    __syncthreads();
    if (ch < 5) { STAGE_B(ch + 1); PROC_A(buf ^ 1); __syncthreads(); buf ^= 1; }
  }

#pragma unroll
  for (int mi = 0; mi < 4; ++mi)
#pragma unroll
    for (int ni = 0; ni < 4; ++ni) {
      const int oc = o0 + ni * 16 + la;
#pragma unroll
      for (int r = 0; r < 4; ++r) {
        const int m = gm0 + m0 + mi * 16 + qg * 4 + r;
        y1[(size_t)m * 256 + oc] = f2b(acc[mi][ni][r]);
      }
    }
#pragma unroll
  for (int ni = 0; ni < 4; ++ni) {
    float s = 0.f, qq = 0.f;
#pragma unroll
    for (int mi = 0; mi < 4; ++mi)
#pragma unroll
      for (int r = 0; r < 4; ++r) {
        const float v = acc[mi][ni][r];
        s += v; qq = fmaf(v, v, qq);
      }
    s += __shfl_xor(s, 16); s += __shfl_xor(s, 32);
    qq += __shfl_xor(qq, 16); qq += __shfl_xor(qq, 32);
    if (lane < 16) {
      sRedS[wm * 256 + o0 + ni * 16 + lane] = s;
      sRedQ[wm * 256 + o0 + ni * 16 + lane] = qq;
    }
  }
  __syncthreads();
  if (tid < 256) {
    part[(size_t)blockIdx.x * 512 + tid] = sRedS[tid] + sRedS[256 + tid];
    part[(size_t)blockIdx.x * 512 + 256 + tid] = sRedQ[tid] + sRedQ[256 + tid];
  }
}

// ---------------- reduce partials -> a,c coefficients ----------------
__global__ __launch_bounds__(1024) void k_reduce(const float* __restrict__ part, int nblk,
                                                 const float* __restrict__ g,
                                                 const float* __restrict__ be,
                                                 float* __restrict__ stats) {
  __shared__ float r0[1024];
  __shared__ float r1[1024];
  const int o = threadIdx.x & 255, q = threadIdx.x >> 8;
  float s = 0.0f, sq = 0.0f;
  for (int i = q; i < nblk; i += 4) {
    s  += part[(size_t)i * 512 + o];
    sq += part[(size_t)i * 512 + 256 + o];
  }
  r0[threadIdx.x] = s; r1[threadIdx.x] = sq;
  __syncthreads();
  if (threadIdx.x < 256) {
    s  = r0[o] + r0[256 + o] + r0[512 + o] + r0[768 + o];
    sq = r1[o] + r1[256 + o] + r1[512 + o] + r1[768 + o];
    const float mean = s * (1.0f / 65536.0f);
    float var = sq * (1.0f / 65536.0f) - mean * mean;
    var = fmaxf(var, 0.0f);
    const float inv = rsqrtf(var + 1e-3f);
    const float a = g[o] * inv;
    stats[o] = a;
    stats[256 + o] = fmaf(-mean, a, be[o]);
  }
}

// ---------------- GEMM2: y2[m][256] = relu(bn(y1)) x W2^T (in-place over y1) -------
__global__ __launch_bounds__(512, 4) void k_gemm2(
    ushort_t* y1, const ushort_t* __restrict__ Wb,
    const float* __restrict__ st1, float* __restrict__ part) {
  __shared__ __align__(16) ushort_t As[2][128 * 72];
  __shared__ __align__(16) ushort_t Bs[256 * 64];
  __shared__ float sSt[512];
  __shared__ float sRedS[512];
  __shared__ float sRedQ[512];

  const int tid = threadIdx.x;
  const int gm0 = blockIdx.x * 128;
  const int lane = tid & 63, wv = tid >> 6;
  const int wm = wv >> 2, wn = wv & 3;
  const int la = lane & 15, qg = lane >> 4;
  const int m0 = wm * 64, o0 = wn * 64;
  const int ar = tid >> 3, ac = tid & 7, rb2 = ar + 64;

  if (tid < 512) sSt[tid] = st1[tid];
  __syncthreads();

  f32x4 acc[4][4];
#pragma unroll
  for (int mi = 0; mi < 4; ++mi)
#pragma unroll
    for (int ni = 0; ni < 4; ++ni) acc[mi][ni] = 0.0f;

  ushort8 g0, g3;
  auto LOAD_A = [&](int ch) {
    const size_t base = (size_t)(gm0 + ar) * 256 + ch * 64 + ac * 8;
    g0 = *(const ushort8*)&y1[base];
    g3 = *(const ushort8*)&y1[base + (size_t)64 * 256];
  };
  auto PROC_A = [&](int ch, int dst) {
    const int k0 = ch * 64 + ac * 8;
    ushort8 oa, ob;
#pragma unroll
    for (int j = 0; j < 8; ++j) {
      const float a = sSt[k0 + j], cc = sSt[256 + k0 + j];
      oa[j] = f2b(fmaxf(fmaf(b2f(g0[j]), a, cc), 0.0f));
      ob[j] = f2b(fmaxf(fmaf(b2f(g3[j]), a, cc), 0.0f));
    }
    *(ushort8*)&As[dst][ar * 72 + ac * 8] = oa;
    *(ushort8*)&As[dst][rb2 * 72 + ac * 8] = ob;
  };
  auto STAGE_B = [&](int ch) {
    const int kbase = ch * 64;
#pragma unroll
    for (int i = 0; i < 4; ++i) {
      const int fc = i * 512 + tid;
      const int row = fc >> 3, p = fc & 7;
      const int cc = p ^ (row & 7);
      gl_lds16(&Wb[(size_t)row * 256 + kbase + cc * 8], &Bs[i * 4096 + wv * 512]);
    }
  };
  auto COMPUTE = [&](int src) {
#pragma unroll
    for (int ks = 0; ks < 2; ++ks) {
      ushort8 af[4], bfr[4];
#pragma unroll
      for (int mi = 0; mi < 4; ++mi)
        af[mi] = *(const ushort8*)&As[src][(m0 + mi * 16 + la) * 72 + (ks * 4 + qg) * 8];
#pragma unroll
      for (int ni = 0; ni < 4; ++ni) {
        const int ro = o0 + ni * 16 + la;
        bfr[ni] = *(const ushort8*)&Bs[ro * 64 + (((ks * 4 + qg) ^ (ro & 7))) * 8];
      }
#pragma unroll
      for (int mi = 0; mi < 4; ++mi)
#pragma unroll
        for (int ni = 0; ni < 4; ++ni)
          acc[mi][ni] = mfma16(af[mi], bfr[ni], acc[mi][ni]);
    }
  };

  STAGE_B(0); LOAD_A(0); PROC_A(0, 0);
  __syncthreads();
  int buf = 0;
  for (int ch = 0; ch < 4; ++ch) {
    if (ch < 3) LOAD_A(ch + 1);
    COMPUTE(buf);
    __syncthreads();
    if (ch < 3) { STAGE_B(ch + 1); PROC_A(ch + 1, buf ^ 1); __syncthreads(); buf ^= 1; }
  }

#pragma unroll
  for (int mi = 0; mi < 4; ++mi)
#pragma unroll
    for (int ni = 0; ni < 4; ++ni) {
      const int oc = o0 + ni * 16 + la;
#pragma unroll
      for (int r = 0; r < 4; ++r) {
        const int m = gm0 + m0 + mi * 16 + qg * 4 + r;
        y1[(size_t)m * 256 + oc] = f2b(acc[mi][ni][r]);
      }
    }
#pragma unroll
  for (int ni = 0; ni < 4; ++ni) {
    float s = 0.f, qq = 0.f;
#pragma unroll
    for (int mi = 0; mi < 4; ++mi)
#pragma unroll
      for (int r = 0; r < 4; ++r) {
        const float v = acc[mi][ni][r];
        s += v; qq = fmaf(v, v, qq);
      }
    s += __shfl_xor(s, 16); s += __shfl_xor(s, 32);
    qq += __shfl_xor(qq, 16); qq += __shfl_xor(qq, 32);
    if (lane < 16) {
      sRedS[wm * 256 + o0 + ni * 16 + lane] = s;
      sRedQ[wm * 256 + o0 + ni * 16 + lane] = qq;
    }
  }
  __syncthreads();
  if (tid < 256) {
    part[(size_t)blockIdx.x * 512 + tid] = sRedS[tid] + sRedS[256 + tid];
    part[(size_t)blockIdx.x * 512 + 256 + tid] = sRedQ[tid] + sRedQ[256 + tid];
  }
}

// ---------------- final: BN+ReLU + transpose y2[m][o] -> out[b][o][n] (f32) --------
__global__ __launch_bounds__(256) void k_final(const ushort_t* __restrict__ y2,
                                               const float* __restrict__ st2,
                                               float* __restrict__ out) {
  __shared__ __align__(16) ushort_t tile[64 * 264];
  const int t = threadIdx.x;
  const int n0 = blockIdx.x * 64;
  const int b = blockIdx.y;
#pragma unroll
  for (int r = 0; r < 8; ++r) {
    const int id = r * 256 + t;
    const int row = id >> 5, c8 = id & 31;
    *(ushort8*)&tile[row * 264 + c8 * 8] =
        *(const ushort8*)&y2[((size_t)b * N2_ + n0 + row) * 256 + c8 * 8];
  }
  __syncthreads();
#pragma unroll
  for (int r = 0; r < 16; ++r) {
    const int id = r * 256 + t;
    const int o = id >> 4, nq = id & 15;
    const float a = st2[o], c = st2[256 + o];
    float4 v;
    v.x = fmaxf(fmaf(b2f(tile[(nq * 4 + 0) * 264 + o]), a, c), 0.0f);
    v.y = fmaxf(fmaf(b2f(tile[(nq * 4 + 1) * 264 + o]), a, c), 0.0f);
    v.z = fmaxf(fmaf(b2f(tile[(nq * 4 + 2) * 264 + o]), a, c), 0.0f);
    v.w = fmaxf(fmaf(b2f(tile[(nq * 4 + 3) * 264 + o]), a, c), 0.0f);
    *(float4*)&out[((size_t)b * 256 + o) * N2_ + n0 + nq * 4] = v;
  }
}

extern "C" void kernel_launch(void* const* d_in, const int* in_sizes, int n_in,
                              void* d_out, int out_size, void* d_ws, size_t ws_size,
                              hipStream_t stream) {
  (void)in_sizes; (void)n_in; (void)out_size; (void)ws_size;
  const float* xyz2  = (const float*)d_in[0];
  const float* xyz1  = (const float*)d_in[1];
  const float* feat2 = (const float*)d_in[2];
  const float* feat1 = (const float*)d_in[3];
  const float* W1  = (const float*)d_in[4];
  const float* g1  = (const float*)d_in[6];
  const float* be1 = (const float*)d_in[7];
  const float* W2  = (const float*)d_in[8];
  const float* g2  = (const float*)d_in[10];
  const float* be2 = (const float*)d_in[11];
  float* out = (float*)d_out;

  char* ws = (char*)d_ws;
  // y1 (33.5MB) overlays f1tb (8.4MB): f1tb dead before gemm1 writes y1
  ushort_t* y1    = (ushort_t*)(ws);               // 33,554,432
  ushort_t* f1tb  = (ushort_t*)(ws);               //  8,388,608 (steps 1-2 only)
  ushort_t* xcat  = (ushort_t*)(ws + 33554432);    // 50,331,648
  ushort_t* W1b   = (ushort_t*)(ws + 83886080);    //    196,608
  ushort_t* W2b   = (ushort_t*)(ws + 84082688);    //    131,072
  float*    part1 = (float*)(ws + 84213760);       //  1,048,576
  float*    part2 = (float*)(ws + 85262336);       //  1,048,576
  float*    st1   = (float*)(ws + 86310912);       //      2,048
  float*    st2   = (float*)(ws + 86312960);       //      2,048

  k_tcvt<<<dim3(64, 8, 8), dim3(32, 8), 0, stream>>>(feat1, f1tb, 256, 2048);
  k_three_nn<<<dim3(128, 8), 256, 0, stream>>>(xyz2, xyz1, f1tb, xcat);
  k_t2x<<<dim3(256, 4, 8), dim3(32, 8), 0, stream>>>(feat2, xcat);
  k_wcvt2<<<160, 256, 0, stream>>>(W1, W2, W1b, W2b);
  k_gemm1<<<512, 512, 0, stream>>>(xcat, W1b, y1, part1);
  k_reduce<<<1, 1024, 0, stream>>>(part1, 512, g1, be1, st1);
  k_gemm2<<<512, 512, 0, stream>>>(y1, W2b, st1, part2);
  k_reduce<<<1, 1024, 0, stream>>>(part2, 512, g2, be2, st2);
  k_final<<<dim3(128, 8), 256, 0, stream>>>(y1, st2, out);
}

// Round 6
// 209.189 us; speedup vs baseline: 1.0544x; 1.0544x over previous
//
#include <hip/hip_runtime.h>
#include <stdint.h>

#define B_   8
#define N1_  2048
#define N2_  8192

typedef unsigned short ushort_t;
typedef __attribute__((ext_vector_type(8))) short short8;
typedef __attribute__((ext_vector_type(8))) unsigned short ushort8;
typedef __attribute__((ext_vector_type(4))) unsigned short ushort4v;
typedef __attribute__((ext_vector_type(4))) float f32x4;

__device__ __forceinline__ float b2f(unsigned short u) {
  union { unsigned int i; float f; } v;
  v.i = ((unsigned int)u) << 16;
  return v.f;
}
__device__ __forceinline__ unsigned short f2b(float f) {  // RNE bf16 round
  unsigned int x = __builtin_bit_cast(unsigned int, f);
  unsigned int r = x + 0x7FFFu + ((x >> 16) & 1u);
  return (unsigned short)(r >> 16);
}
__device__ __forceinline__ f32x4 mfma16(ushort8 a, ushort8 b, f32x4 c) {
  return __builtin_amdgcn_mfma_f32_16x16x32_bf16(
      __builtin_bit_cast(short8, a), __builtin_bit_cast(short8, b), c, 0, 0, 0);
}
__device__ __forceinline__ void gl_lds16(const void* gsrc, void* ldst) {
  __builtin_amdgcn_global_load_lds(
      (const __attribute__((address_space(1))) unsigned int*)(uintptr_t)gsrc,
      (__attribute__((address_space(3))) unsigned int*)(uint32_t)(uintptr_t)ldst,
      16, 0, 0);
}

// ---- three_nn + interp fused: 8 threads/query; writes xcat[m][384] cols 0..255 ----
__global__ __launch_bounds__(256) void k_three_nn(const float* __restrict__ xyz2,
                                                  const float* __restrict__ xyz1,
                                                  const ushort_t* __restrict__ f1tb,
                                                  ushort_t* __restrict__ xcat) {
  // chunk-padded [3][8][264]: 8 chunk bases map to banks {0,8,16,24}x2 -> 2-way (free)
  __shared__ __align__(16) float sm[3][8 * 264];
  const int b = blockIdx.y;
  const float* p1 = xyz1 + (size_t)b * 3 * N1_;
  for (int i = threadIdx.x; i < N1_; i += 256) {
    const int a = (i >> 8) * 264 + (i & 255);
    sm[0][a] = p1[i];
    sm[1][a] = p1[N1_ + i];
    sm[2][a] = p1[2 * N1_ + i];
  }
  __syncthreads();

  const int lane = threadIdx.x & 63;
  const int q = threadIdx.x >> 3, c = threadIdx.x & 7;
  const int n = blockIdx.x * 32 + q;
  const float px = xyz2[(size_t)b * 3 * N2_ + n];
  const float py = xyz2[(size_t)b * 3 * N2_ + N2_ + n];
  const float pz = xyz2[(size_t)b * 3 * N2_ + 2 * N2_ + n];

  float dk0 = 3.4e38f, dk1 = 3.4e38f, dk2 = 3.4e38f;
  int ik0 = 0, ik1 = 0, ik2 = 0;
  const float* mx = &sm[0][c * 264];
  const float* my = &sm[1][c * 264];
  const float* mz = &sm[2][c * 264];

  // exact insert: cmps on OLD values, dist update via med3, idx via cndmask
#define INS(DD, II)                                   \
  {                                                   \
    const float d_ = (DD); const int i_ = (II);       \
    const bool c0_ = d_ < dk0;                        \
    const bool c1_ = d_ < dk1;                        \
    const bool c2_ = d_ < dk2;                        \
    ik2 = c2_ ? (c1_ ? ik1 : i_) : ik2;               \
    ik1 = c1_ ? (c0_ ? ik0 : i_) : ik1;               \
    ik0 = c0_ ? i_ : ik0;                             \
    dk2 = __builtin_amdgcn_fmed3f(dk1, dk2, d_);      \
    dk1 = __builtin_amdgcn_fmed3f(dk0, dk1, d_);      \
    dk0 = fminf(dk0, d_);                             \
  }

  const int ib = c * 256;
  for (int i = 0; i < 256; i += 8) {
    const float4 xa = *(const float4*)(mx + i);
    const float4 ya = *(const float4*)(my + i);
    const float4 za = *(const float4*)(mz + i);
    const float4 xb = *(const float4*)(mx + i + 4);
    const float4 yb = *(const float4*)(my + i + 4);
    const float4 zb = *(const float4*)(mz + i + 4);
#define CAND(J, XX, YY, ZZ)                                 \
    {                                                       \
      const float dx = (XX) - px;                           \
      const float dy = (YY) - py;                           \
      const float dz = (ZZ) - pz;                           \
      const float dd = fmaf(dx, dx, fmaf(dy, dy, dz * dz)); \
      INS(dd, ib + i + (J))                                 \
    }
    CAND(0, xa.x, ya.x, za.x) CAND(1, xa.y, ya.y, za.y)
    CAND(2, xa.z, ya.z, za.z) CAND(3, xa.w, ya.w, za.w)
    CAND(4, xb.x, yb.x, zb.x) CAND(5, xb.y, yb.y, zb.y)
    CAND(6, xb.z, yb.z, zb.z) CAND(7, xb.w, yb.w, zb.w)
#undef CAND
  }

  // butterfly merge across the 8 chunk lanes of this query
#pragma unroll
  for (int d = 1; d <= 4; d <<= 1) {
    const float r0 = __shfl_xor(dk0, d);
    const float r1 = __shfl_xor(dk1, d);
    const float r2 = __shfl_xor(dk2, d);
    const int s0 = __shfl_xor(ik0, d);
    const int s1 = __shfl_xor(ik1, d);
    const int s2 = __shfl_xor(ik2, d);
    INS(r0, s0) INS(r1, s1) INS(r2, s2)
  }
#undef INS

  // tie-correct indices live on the group leader (lowest chunk) -> broadcast
  const int lq = lane & ~7;
  const int i0 = __shfl(ik0, lq);
  const int i1 = __shfl(ik1, lq);
  const int i2 = __shfl(ik2, lq);
  const float e0 = fmaxf(dk0, 1e-10f);
  const float e1 = fmaxf(dk1, 1e-10f);
  const float e2 = fmaxf(dk2, 1e-10f);
  const float v0 = 1.0f / e0, v1 = 1.0f / e1, v2 = 1.0f / e2;
  const float rs = 1.0f / (v0 + v1 + v2);
  const float w0 = v0 * rs, w1 = v1 * rs, w2 = v2 * rs;

  // fused interp: each chunk-thread writes its 32-channel slice of xcat row n
  const ushort_t* f1base = f1tb + (size_t)b * (N1_ * 256) + c * 32;
  const ushort_t* r0p = f1base + (size_t)i0 * 256;
  const ushort_t* r1p = f1base + (size_t)i1 * 256;
  const ushort_t* r2p = f1base + (size_t)i2 * 256;
  ushort_t* outp = xcat + ((size_t)b * N2_ + n) * 384 + c * 32;
#pragma unroll
  for (int u = 0; u < 4; ++u) {
    const ushort8 a8 = *(const ushort8*)&r0p[u * 8];
    const ushort8 b8 = *(const ushort8*)&r1p[u * 8];
    const ushort8 c8 = *(const ushort8*)&r2p[u * 8];
    ushort8 o;
#pragma unroll
    for (int j = 0; j < 8; ++j)
      o[j] = f2b(w0 * b2f(a8[j]) + w1 * b2f(b8[j]) + w2 * b2f(c8[j]));
    *(ushort8*)&outp[u * 8] = o;
  }
}

// ------------- transpose + f32->bf16: feat1[b][256][2048] -> f1tb[(b*2048+n)][256] --
__global__ __launch_bounds__(256) void k_tcvt(const float* __restrict__ in,
                                              ushort_t* __restrict__ out, int R, int C) {
  __shared__ float t[32][33];
  const int b = blockIdx.z;
  const float* pin = in + (size_t)b * R * C;
  ushort_t* pout = out + (size_t)b * R * C;
  const int c0 = blockIdx.x * 32, r0 = blockIdx.y * 32;
  const int tx = threadIdx.x, ty = threadIdx.y;
#pragma unroll
  for (int j = 0; j < 4; ++j)
    t[ty * 4 + j][tx] = pin[(size_t)(r0 + ty * 4 + j) * C + c0 + tx];
  __syncthreads();
#pragma unroll
  for (int j = 0; j < 4; ++j)
    pout[(size_t)(c0 + ty * 4 + j) * R + r0 + tx] = f2b(t[tx][ty * 4 + j]);
}

// ---- feat2[b][128][8192] -> xcat[m][384] cols 256..383 (transpose + cvt) ---------
__global__ __launch_bounds__(256) void k_t2x(const float* __restrict__ feat2,
                                             ushort_t* __restrict__ xcat) {
  __shared__ float t[32][33];
  const int b = blockIdx.z;
  const int n0 = blockIdx.x * 32, c0 = blockIdx.y * 32;
  const int tx = threadIdx.x, ty = threadIdx.y;
  const float* pin = feat2 + (size_t)b * 128 * N2_;
#pragma unroll
  for (int j = 0; j < 4; ++j)
    t[ty * 4 + j][tx] = pin[(size_t)(c0 + ty * 4 + j) * N2_ + n0 + tx];
  __syncthreads();
  const int tt = ty * 32 + tx;
  const int nr = tt >> 3, cg = tt & 7;
  ushort4v o;
#pragma unroll
  for (int j = 0; j < 4; ++j)
    o[j] = f2b(t[cg * 4 + j][nr]);
  *(ushort4v*)&xcat[((size_t)b * N2_ + n0 + nr) * 384 + 256 + c0 + cg * 4] = o;
}

// ---------------- W1 + W2 f32 -> bf16 in one launch ----------------
__global__ __launch_bounds__(256) void k_wcvt2(const float* __restrict__ W1,
                                               const float* __restrict__ W2,
                                               ushort_t* __restrict__ W1b,
                                               ushort_t* __restrict__ W2b) {
  const int i = (blockIdx.x * 256 + threadIdx.x) * 4;
  const float* src; ushort_t* dst; int off;
  if (i < 98304) { src = W1; dst = W1b; off = i; }
  else { off = i - 98304; if (off >= 65536) return; src = W2; dst = W2b; }
  const float4 v = *(const float4*)&src[off];
  ushort4v o;
  o[0] = f2b(v.x); o[1] = f2b(v.y); o[2] = f2b(v.z); o[3] = f2b(v.w);
  *(ushort4v*)&dst[off] = o;
}

// ---------------- GEMM1: y1[m][256] = xcat x W1^T, A and B via global_load_lds ------
__global__ __launch_bounds__(512, 4) void k_gemm1(
    const ushort_t* __restrict__ xcat, const ushort_t* __restrict__ Wb,
    ushort_t* __restrict__ y1, float* __restrict__ part) {
  __shared__ __align__(16) ushort_t As[2][128 * 64];
  __shared__ __align__(16) ushort_t Bs[256 * 64];
  __shared__ float sRedS[512];
  __shared__ float sRedQ[512];

  const int tid = threadIdx.x;
  const int gm0 = blockIdx.x * 128;
  const int lane = tid & 63, wv = tid >> 6;
  const int wm = wv >> 2, wn = wv & 3;
  const int la = lane & 15, qg = lane >> 4;
  const int m0 = wm * 64, o0 = wn * 64;

  f32x4 acc[4][4];
#pragma unroll
  for (int mi = 0; mi < 4; ++mi)
#pragma unroll
    for (int ni = 0; ni < 4; ++ni) acc[mi][ni] = 0.0f;

  auto STAGE_A = [&](int ch, int dst) {
    // 128 rows x 64 k: linear LDS dest, inverse-swizzled source column (rule 21)
#pragma unroll
    for (int i = 0; i < 2; ++i) {
      const int fc = i * 512 + tid;
      const int row = fc >> 3, p = fc & 7;
      const int cc = p ^ (row & 7);
      gl_lds16(&xcat[(size_t)(gm0 + row) * 384 + ch * 64 + cc * 8],
               &As[dst][i * 4096 + wv * 512]);
    }
  };
  auto STAGE_B = [&](int ch) {
    const int kbase = ch * 64;
#pragma unroll
    for (int i = 0; i < 4; ++i) {
      const int fc = i * 512 + tid;
      const int row = fc >> 3, p = fc & 7;
      const int cc = p ^ (row & 7);
      gl_lds16(&Wb[(size_t)row * 384 + kbase + cc * 8], &Bs[i * 4096 + wv * 512]);
    }
  };
  auto COMPUTE = [&](int src) {
#pragma unroll
    for (int ks = 0; ks < 2; ++ks) {
      ushort8 af[4], bfr[4];
#pragma unroll
      for (int mi = 0; mi < 4; ++mi) {
        const int rm = m0 + mi * 16 + la;
        af[mi] = *(const ushort8*)&As[src][rm * 64 + (((ks * 4 + qg) ^ (rm & 7))) * 8];
      }
#pragma unroll
      for (int ni = 0; ni < 4; ++ni) {
        const int ro = o0 + ni * 16 + la;
        bfr[ni] = *(const ushort8*)&Bs[ro * 64 + (((ks * 4 + qg) ^ (ro & 7))) * 8];
      }
#pragma unroll
      for (int mi = 0; mi < 4; ++mi)
#pragma unroll
        for (int ni = 0; ni < 4; ++ni)
          acc[mi][ni] = mfma16(af[mi], bfr[ni], acc[mi][ni]);
    }
  };

  STAGE_A(0, 0); STAGE_B(0);
  __syncthreads();
  int buf = 0;
  for (int ch = 0; ch < 6; ++ch) {
    if (ch < 5) STAGE_A(ch + 1, buf ^ 1);
    COMPUTE(buf);
    __syncthreads();
    if (ch < 5) { STAGE_B(ch + 1); __syncthreads(); }
    buf ^= 1;
  }

#pragma unroll
  for (int mi = 0; mi < 4; ++mi)
#pragma unroll
    for (int ni = 0; ni < 4; ++ni) {
      const int oc = o0 + ni * 16 + la;
#pragma unroll
      for (int r = 0; r < 4; ++r) {
        const int m = gm0 + m0 + mi * 16 + qg * 4 + r;
        y1[(size_t)m * 256 + oc] = f2b(acc[mi][ni][r]);
      }
    }
#pragma unroll
  for (int ni = 0; ni < 4; ++ni) {
    float s = 0.f, qq = 0.f;
#pragma unroll
    for (int mi = 0; mi < 4; ++mi)
#pragma unroll
      for (int r = 0; r < 4; ++r) {
        const float v = acc[mi][ni][r];
        s += v; qq = fmaf(v, v, qq);
      }
    s += __shfl_xor(s, 16); s += __shfl_xor(s, 32);
    qq += __shfl_xor(qq, 16); qq += __shfl_xor(qq, 32);
    if (lane < 16) {
      sRedS[wm * 256 + o0 + ni * 16 + lane] = s;
      sRedQ[wm * 256 + o0 + ni * 16 + lane] = qq;
    }
  }
  __syncthreads();
  if (tid < 256) {
    part[(size_t)blockIdx.x * 512 + tid] = sRedS[tid] + sRedS[256 + tid];
    part[(size_t)blockIdx.x * 512 + 256 + tid] = sRedQ[tid] + sRedQ[256 + tid];
  }
}

// ---------------- reduce partials -> a,c coefficients ----------------
__global__ __launch_bounds__(1024) void k_reduce(const float* __restrict__ part, int nblk,
                                                 const float* __restrict__ g,
                                                 const float* __restrict__ be,
                                                 float* __restrict__ stats) {
  __shared__ float r0[1024];
  __shared__ float r1[1024];
  const int o = threadIdx.x & 255, q = threadIdx.x >> 8;
  float s = 0.0f, sq = 0.0f;
  for (int i = q; i < nblk; i += 4) {
    s  += part[(size_t)i * 512 + o];
    sq += part[(size_t)i * 512 + 256 + o];
  }
  r0[threadIdx.x] = s; r1[threadIdx.x] = sq;
  __syncthreads();
  if (threadIdx.x < 256) {
    s  = r0[o] + r0[256 + o] + r0[512 + o] + r0[768 + o];
    sq = r1[o] + r1[256 + o] + r1[512 + o] + r1[768 + o];
    const float mean = s * (1.0f / 65536.0f);
    float var = sq * (1.0f / 65536.0f) - mean * mean;
    var = fmaxf(var, 0.0f);
    const float inv = rsqrtf(var + 1e-3f);
    const float a = g[o] * inv;
    stats[o] = a;
    stats[256 + o] = fmaf(-mean, a, be[o]);
  }
}

// ---------------- GEMM2: y2[m][256] = relu(bn(y1)) x W2^T (in-place over y1) -------
__global__ __launch_bounds__(512, 4) void k_gemm2(
    ushort_t* y1, const ushort_t* __restrict__ Wb,
    const float* __restrict__ st1, float* __restrict__ part) {
  __shared__ __align__(16) ushort_t As[2][128 * 72];
  __shared__ __align__(16) ushort_t Bs[256 * 64];
  __shared__ float sSt[512];
  __shared__ float sRedS[512];
  __shared__ float sRedQ[512];

  const int tid = threadIdx.x;
  const int gm0 = blockIdx.x * 128;
  const int lane = tid & 63, wv = tid >> 6;
  const int wm = wv >> 2, wn = wv & 3;
  const int la = lane & 15, qg = lane >> 4;
  const int m0 = wm * 64, o0 = wn * 64;
  const int ar = tid >> 3, ac = tid & 7, rb2 = ar + 64;

  if (tid < 512) sSt[tid] = st1[tid];
  __syncthreads();

  f32x4 acc[4][4];
#pragma unroll
  for (int mi = 0; mi < 4; ++mi)
#pragma unroll
    for (int ni = 0; ni < 4; ++ni) acc[mi][ni] = 0.0f;

  ushort8 g0, g3;
  auto LOAD_A = [&](int ch) {
    const size_t base = (size_t)(gm0 + ar) * 256 + ch * 64 + ac * 8;
    g0 = *(const ushort8*)&y1[base];
    g3 = *(const ushort8*)&y1[base + (size_t)64 * 256];
  };
  auto PROC_A = [&](int ch, int dst) {
    const int k0 = ch * 64 + ac * 8;
    ushort8 oa, ob;
#pragma unroll
    for (int j = 0; j < 8; ++j) {
      const float a = sSt[k0 + j], cc = sSt[256 + k0 + j];
      oa[j] = f2b(fmaxf(fmaf(b2f(g0[j]), a, cc), 0.0f));
      ob[j] = f2b(fmaxf(fmaf(b2f(g3[j]), a, cc), 0.0f));
    }
    *(ushort8*)&As[dst][ar * 72 + ac * 8] = oa;
    *(ushort8*)&As[dst][rb2 * 72 + ac * 8] = ob;
  };
  auto STAGE_B = [&](int ch) {
    const int kbase = ch * 64;
#pragma unroll
    for (int i = 0; i < 4; ++i) {
      const int fc = i * 512 + tid;
      const int row = fc >> 3, p = fc & 7;
      const int cc = p ^ (row & 7);
      gl_lds16(&Wb[(size_t)row * 256 + kbase + cc * 8], &Bs[i * 4096 + wv * 512]);
    }
  };
  auto COMPUTE = [&](int src) {
#pragma unroll
    for (int ks = 0; ks < 2; ++ks) {
      ushort8 af[4], bfr[4];
#pragma unroll
      for (int mi = 0; mi < 4; ++mi)
        af[mi] = *(const ushort8*)&As[src][(m0 + mi * 16 + la) * 72 + (ks * 4 + qg) * 8];
#pragma unroll
      for (int ni = 0; ni < 4; ++ni) {
        const int ro = o0 + ni * 16 + la;
        bfr[ni] = *(const ushort8*)&Bs[ro * 64 + (((ks * 4 + qg) ^ (ro & 7))) * 8];
      }
#pragma unroll
      for (int mi = 0; mi < 4; ++mi)
#pragma unroll
        for (int ni = 0; ni < 4; ++ni)
          acc[mi][ni] = mfma16(af[mi], bfr[ni], acc[mi][ni]);
    }
  };

  STAGE_B(0); LOAD_A(0); PROC_A(0, 0);
  __syncthreads();
  int buf = 0;
  for (int ch = 0; ch < 4; ++ch) {
    if (ch < 3) LOAD_A(ch + 1);
    COMPUTE(buf);
    __syncthreads();
    if (ch < 3) { STAGE_B(ch + 1); PROC_A(ch + 1, buf ^ 1); __syncthreads(); buf ^= 1; }
  }

#pragma unroll
  for (int mi = 0; mi < 4; ++mi)
#pragma unroll
    for (int ni = 0; ni < 4; ++ni) {
      const int oc = o0 + ni * 16 + la;
#pragma unroll
      for (int r = 0; r < 4; ++r) {
        const int m = gm0 + m0 + mi * 16 + qg * 4 + r;
        y1[(size_t)m * 256 + oc] = f2b(acc[mi][ni][r]);
      }
    }
#pragma unroll
  for (int ni = 0; ni < 4; ++ni) {
    float s = 0.f, qq = 0.f;
#pragma unroll
    for (int mi = 0; mi < 4; ++mi)
#pragma unroll
      for (int r = 0; r < 4; ++r) {
        const float v = acc[mi][ni][r];
        s += v; qq = fmaf(v, v, qq);
      }
    s += __shfl_xor(s, 16); s += __shfl_xor(s, 32);
    qq += __shfl_xor(qq, 16); qq += __shfl_xor(qq, 32);
    if (lane < 16) {
      sRedS[wm * 256 + o0 + ni * 16 + lane] = s;
      sRedQ[wm * 256 + o0 + ni * 16 + lane] = qq;
    }
  }
  __syncthreads();
  if (tid < 256) {
    part[(size_t)blockIdx.x * 512 + tid] = sRedS[tid] + sRedS[256 + tid];
    part[(size_t)blockIdx.x * 512 + 256 + tid] = sRedQ[tid] + sRedQ[256 + tid];
  }
}

// ---------------- final: BN+ReLU + transpose y2[m][o] -> out[b][o][n] (f32) --------
__global__ __launch_bounds__(256) void k_final(const ushort_t* __restrict__ y2,
                                               const float* __restrict__ st2,
                                               float* __restrict__ out) {
  __shared__ __align__(16) ushort_t tile[64 * 264];
  const int t = threadIdx.x;
  const int n0 = blockIdx.x * 64;
  const int b = blockIdx.y;
#pragma unroll
  for (int r = 0; r < 8; ++r) {
    const int id = r * 256 + t;
    const int row = id >> 5, c8 = id & 31;
    *(ushort8*)&tile[row * 264 + c8 * 8] =
        *(const ushort8*)&y2[((size_t)b * N2_ + n0 + row) * 256 + c8 * 8];
  }
  __syncthreads();
#pragma unroll
  for (int r = 0; r < 16; ++r) {
    const int id = r * 256 + t;
    const int o = id >> 4, nq = id & 15;
    const float a = st2[o], c = st2[256 + o];
    float4 v;
    v.x = fmaxf(fmaf(b2f(tile[(nq * 4 + 0) * 264 + o]), a, c), 0.0f);
    v.y = fmaxf(fmaf(b2f(tile[(nq * 4 + 1) * 264 + o]), a, c), 0.0f);
    v.z = fmaxf(fmaf(b2f(tile[(nq * 4 + 2) * 264 + o]), a, c), 0.0f);
    v.w = fmaxf(fmaf(b2f(tile[(nq * 4 + 3) * 264 + o]), a, c), 0.0f);
    *(float4*)&out[((size_t)b * 256 + o) * N2_ + n0 + nq * 4] = v;
  }
}

extern "C" void kernel_launch(void* const* d_in, const int* in_sizes, int n_in,
                              void* d_out, int out_size, void* d_ws, size_t ws_size,
                              hipStream_t stream) {
  (void)in_sizes; (void)n_in; (void)out_size; (void)ws_size;
  const float* xyz2  = (const float*)d_in[0];
  const float* xyz1  = (const float*)d_in[1];
  const float* feat2 = (const float*)d_in[2];
  const float* feat1 = (const float*)d_in[3];
  const float* W1  = (const float*)d_in[4];
  const float* g1  = (const float*)d_in[6];
  const float* be1 = (const float*)d_in[7];
  const float* W2  = (const float*)d_in[8];
  const float* g2  = (const float*)d_in[10];
  const float* be2 = (const float*)d_in[11];
  float* out = (float*)d_out;

  char* ws = (char*)d_ws;
  // y1 (33.5MB) overlays f1tb (8.4MB): f1tb dead before gemm1 writes y1
  ushort_t* y1    = (ushort_t*)(ws);               // 33,554,432
  ushort_t* f1tb  = (ushort_t*)(ws);               //  8,388,608 (steps 1-2 only)
  ushort_t* xcat  = (ushort_t*)(ws + 33554432);    // 50,331,648
  ushort_t* W1b   = (ushort_t*)(ws + 83886080);    //    196,608
  ushort_t* W2b   = (ushort_t*)(ws + 84082688);    //    131,072
  float*    part1 = (float*)(ws + 84213760);       //  1,048,576
  float*    part2 = (float*)(ws + 85262336);       //  1,048,576
  float*    st1   = (float*)(ws + 86310912);       //      2,048
  float*    st2   = (float*)(ws + 86312960);       //      2,048

  k_tcvt<<<dim3(64, 8, 8), dim3(32, 8), 0, stream>>>(feat1, f1tb, 256, 2048);
  k_three_nn<<<dim3(256, 8), 256, 0, stream>>>(xyz2, xyz1, f1tb, xcat);
  k_t2x<<<dim3(256, 4, 8), dim3(32, 8), 0, stream>>>(feat2, xcat);
  k_wcvt2<<<160, 256, 0, stream>>>(W1, W2, W1b, W2b);
  k_gemm1<<<512, 512, 0, stream>>>(xcat, W1b, y1, part1);
  k_reduce<<<1, 1024, 0, stream>>>(part1, 512, g1, be1, st1);
  k_gemm2<<<512, 512, 0, stream>>>(y1, W2b, st1, part2);
  k_reduce<<<1, 1024, 0, stream>>>(part2, 512, g2, be2, st2);
  k_final<<<dim3(128, 8), 256, 0, stream>>>(y1, st2, out);
}